// Round 6
// baseline (125.297 us; speedup 1.0000x reference)
//
#include <hip/hip_runtime.h>

// RandomSelfAttention: B=2, S=4096, S2=2048, NH=8, H=64, NKEYS=64
// q:(B,S2,NH,H) f32, k/v:(B,S,NH,H) f32, idx:(B,S2,NKEYS) int
// out z:(B,S2,NH,H) f32
//
// One wave per (b,q,n). Lane = (g=lane>>4, hc=lane&15).
// Round 6 structure: EXPLICIT load-batching. Phase1 loads ALL 16 k-rows
// into kr[16] (64 VGPRs, 16 loads in flight = one latency wall), then does
// the dots + 4-step shfl_xor butterflies. Phase2 same for v into vr[16]
// (kr dead by then, regs reused). Round-5 post-mortem: implicit prefetch
// was sunk by the compiler (VGPR stayed 60); holding ONE array at a time
// fits the (256,4)=128-VGPR budget so the compiler can't split it.
// Offsets re-broadcast via __shfl in each loop (cheaper than a 16-reg
// offs array that risks spill).
// Block swizzle: blockIdx%16 = (b,n) combo -> per-XCD L2 working set ~4MB.
//
// DO NOT tighten to (256,8): round 3 spilled 750MB scratch. Watch
// WRITE_SIZE (8MB = clean) and VGPR_Count (~110 expected) on any edit.

#define BB 2
#define SS 4096
#define S2V 2048
#define NHV 8
#define HV 64
#define NKV 64

__global__ __launch_bounds__(256, 4)
void rsa_kernel(const float* __restrict__ q, const float* __restrict__ k,
                const float* __restrict__ v, const int* __restrict__ idx,
                float* __restrict__ out) {
    const int lane = threadIdx.x & 63;
    const int w    = threadIdx.x >> 6;
    const int bi   = blockIdx.x;

    const int combo = bi & 15;
    const int b     = combo >> 3;
    const int n     = combo & 7;
    const int qi    = ((bi >> 4) << 2) + w;

    const int g  = lane >> 4;    // key group 0..3
    const int hc = lane & 15;    // h-chunk 0..15 (float4 granularity)

    const size_t bq = (size_t)b * S2V + qi;

    // q chunk for this lane (prescaled by h^-0.5 = 1/8)
    const float* qrow = q + (bq * NHV + n) * HV;
    const float4 qv = *(const float4*)(qrow + hc * 4);
    const float4 q4 = make_float4(qv.x * 0.125f, qv.y * 0.125f,
                                  qv.z * 0.125f, qv.w * 0.125f);

    const int my_off = idx[bq * NKV + lane] * (NHV * HV);

    const float* kb = k + ((size_t)b * SS * NHV + n) * HV;
    const float* vb = v + ((size_t)b * SS * NHV + n) * HV;

    // ---- phase 1a: ALL 16 k-row loads issued back-to-back ----
    float4 kr[16];
#pragma unroll
    for (int it = 0; it < 16; ++it) {
        const int off = __shfl(my_off, it * 4 + g, 64);   // key (it*4+g)'s row
        kr[it] = *(const float4*)(kb + off + hc * 4);
    }

    // ---- phase 1b: dots + butterflies (kr dies progressively) ----
    float sc[16];
#pragma unroll
    for (int it = 0; it < 16; ++it) {
        float d = kr[it].x * q4.x + kr[it].y * q4.y
                + kr[it].z * q4.z + kr[it].w * q4.w;
        d += __shfl_xor(d, 1);
        d += __shfl_xor(d, 2);
        d += __shfl_xor(d, 4);
        d += __shfl_xor(d, 8);
        sc[it] = d;   // full dot of key it*4+g, replicated over 16-lane group
    }

    // ---- softmax over 64 keys ----
    float m = sc[0];
#pragma unroll
    for (int it = 1; it < 16; ++it) m = fmaxf(m, sc[it]);
    m = fmaxf(m, __shfl_xor(m, 16));
    m = fmaxf(m, __shfl_xor(m, 32));

    float ssum = 0.f;
#pragma unroll
    for (int it = 0; it < 16; ++it) {
        sc[it] = __expf(sc[it] - m);
        ssum += sc[it];
    }
    ssum += __shfl_xor(ssum, 16);
    ssum += __shfl_xor(ssum, 32);
    const float rs = __frcp_rn(ssum);

    // ---- phase 2a: ALL 16 v-row loads issued back-to-back ----
    float4 vr[16];
#pragma unroll
    for (int it = 0; it < 16; ++it) {
        const int off = __shfl(my_off, it * 4 + g, 64);
        vr[it] = *(const float4*)(vb + off + hc * 4);
    }

    // ---- phase 2b: z = sum_key p[key] * v_row[key] ----
    float4 z = make_float4(0.f, 0.f, 0.f, 0.f);
#pragma unroll
    for (int it = 0; it < 16; ++it) {
        const float p = sc[it];
        z.x = fmaf(p, vr[it].x, z.x);
        z.y = fmaf(p, vr[it].y, z.y);
        z.z = fmaf(p, vr[it].z, z.z);
        z.w = fmaf(p, vr[it].w, z.w);
    }
    // reduce partial z across the 4 key groups
    z.x += __shfl_xor(z.x, 16); z.y += __shfl_xor(z.y, 16);
    z.z += __shfl_xor(z.z, 16); z.w += __shfl_xor(z.w, 16);
    z.x += __shfl_xor(z.x, 32); z.y += __shfl_xor(z.y, 32);
    z.z += __shfl_xor(z.z, 32); z.w += __shfl_xor(z.w, 32);

    if (g == 0) {
        float4 zo = make_float4(z.x * rs, z.y * rs, z.z * rs, z.w * rs);
        *(float4*)(out + (bq * NHV + n) * HV + hc * 4) = zo;
    }
}

extern "C" void kernel_launch(void* const* d_in, const int* in_sizes, int n_in,
                              void* d_out, int out_size, void* d_ws, size_t ws_size,
                              hipStream_t stream) {
    const float* q   = (const float*)d_in[0];
    const float* k   = (const float*)d_in[1];
    const float* v   = (const float*)d_in[2];
    const int*   idx = (const int*)d_in[3];
    float*       out = (float*)d_out;

    const int n_units = BB * S2V * NHV;       // 32768 waves
    const int blocks  = n_units / 4;          // 8192 blocks of 4 waves
    rsa_kernel<<<blocks, 256, 0, stream>>>(q, k, v, idx, out);
}

// Round 7
// 123.803 us; speedup vs baseline: 1.0121x; 1.0121x over previous
//
#include <hip/hip_runtime.h>

// RandomSelfAttention: B=2, S=4096, S2=2048, NH=8, H=64, NKEYS=64
// q:(B,S2,NH,H) f32, k/v:(B,S,NH,H) f32, idx:(B,S2,NKEYS) int
// out z:(B,S2,NH,H) f32
//
// One wave per (b,q,n). Lane = (g=lane>>4, hc=lane&15).
// Structure: 16 k-row loads batched -> dots/butterflies (kr dies) ->
// 16 v-row loads batched -> softmax (VALU/DS only, overlaps v latency) ->
// fma + cross-group reduce.
//
// amdgpu_waves_per_eu(4,4): PINS the occupancy tier at 4 waves/EU (128-VGPR
// budget, min AND max). Rounds 5/6 post-mortem: with only a min bound the
// machine scheduler chased the 8-wave tier (<=64 VGPRs) and re-split every
// explicit load batch (VGPR stayed 56-60, dur stuck at 60us with no pipe
// >36%). Pinning removes the incentive; expected VGPR ~110.
// Round 3 lesson: (256,8) hard cap = 750MB scratch spill. Watch WRITE_SIZE
// (8MB = clean) and VGPR_Count on any edit.
// Block swizzle: blockIdx%16 = (b,n) combo -> per-XCD L2 working set ~4MB.

#define BB 2
#define SS 4096
#define S2V 2048
#define NHV 8
#define HV 64
#define NKV 64

__global__ __launch_bounds__(256)
__attribute__((amdgpu_waves_per_eu(4, 4)))
void rsa_kernel(const float* __restrict__ q, const float* __restrict__ k,
                const float* __restrict__ v, const int* __restrict__ idx,
                float* __restrict__ out) {
    const int lane = threadIdx.x & 63;
    const int w    = threadIdx.x >> 6;
    const int bi   = blockIdx.x;

    const int combo = bi & 15;
    const int b     = combo >> 3;
    const int n     = combo & 7;
    const int qi    = ((bi >> 4) << 2) + w;

    const int g  = lane >> 4;    // key group 0..3
    const int hc = lane & 15;    // h-chunk 0..15 (float4 granularity)

    const size_t bq = (size_t)b * S2V + qi;

    // q chunk for this lane (prescaled by h^-0.5 = 1/8)
    const float* qrow = q + (bq * NHV + n) * HV;
    const float4 qv = *(const float4*)(qrow + hc * 4);
    const float4 q4 = make_float4(qv.x * 0.125f, qv.y * 0.125f,
                                  qv.z * 0.125f, qv.w * 0.125f);

    const int my_off = idx[bq * NKV + lane] * (NHV * HV);

    const float* kb = k + ((size_t)b * SS * NHV + n) * HV;
    const float* vb = v + ((size_t)b * SS * NHV + n) * HV;

    // ---- phase 1a: ALL 16 k-row loads issued back-to-back ----
    float4 kr[16];
#pragma unroll
    for (int it = 0; it < 16; ++it) {
        const int off = __shfl(my_off, it * 4 + g, 64);   // key (it*4+g)'s row
        kr[it] = *(const float4*)(kb + off + hc * 4);
    }

    // ---- phase 1b: dots + butterflies (kr dies progressively) ----
    float sc[16];
#pragma unroll
    for (int it = 0; it < 16; ++it) {
        float d = kr[it].x * q4.x + kr[it].y * q4.y
                + kr[it].z * q4.z + kr[it].w * q4.w;
        d += __shfl_xor(d, 1);
        d += __shfl_xor(d, 2);
        d += __shfl_xor(d, 4);
        d += __shfl_xor(d, 8);
        sc[it] = d;   // full dot of key it*4+g, replicated over 16-lane group
    }

    // ---- phase 2a: ALL 16 v-row loads issued (latency hides under softmax) ----
    float4 vr[16];
#pragma unroll
    for (int it = 0; it < 16; ++it) {
        const int off = __shfl(my_off, it * 4 + g, 64);
        vr[it] = *(const float4*)(vb + off + hc * 4);
    }

    // ---- softmax over 64 keys (pure VALU/DS — no memory dependence) ----
    float m = sc[0];
#pragma unroll
    for (int it = 1; it < 16; ++it) m = fmaxf(m, sc[it]);
    m = fmaxf(m, __shfl_xor(m, 16));
    m = fmaxf(m, __shfl_xor(m, 32));

    float ssum = 0.f;
#pragma unroll
    for (int it = 0; it < 16; ++it) {
        sc[it] = __expf(sc[it] - m);
        ssum += sc[it];
    }
    ssum += __shfl_xor(ssum, 16);
    ssum += __shfl_xor(ssum, 32);
    const float rs = __frcp_rn(ssum);

    // ---- phase 2b: z = sum_key p[key] * v_row[key] ----
    float4 z = make_float4(0.f, 0.f, 0.f, 0.f);
#pragma unroll
    for (int it = 0; it < 16; ++it) {
        const float p = sc[it];
        z.x = fmaf(p, vr[it].x, z.x);
        z.y = fmaf(p, vr[it].y, z.y);
        z.z = fmaf(p, vr[it].z, z.z);
        z.w = fmaf(p, vr[it].w, z.w);
    }
    // reduce partial z across the 4 key groups
    z.x += __shfl_xor(z.x, 16); z.y += __shfl_xor(z.y, 16);
    z.z += __shfl_xor(z.z, 16); z.w += __shfl_xor(z.w, 16);
    z.x += __shfl_xor(z.x, 32); z.y += __shfl_xor(z.y, 32);
    z.z += __shfl_xor(z.z, 32); z.w += __shfl_xor(z.w, 32);

    if (g == 0) {
        float4 zo = make_float4(z.x * rs, z.y * rs, z.z * rs, z.w * rs);
        *(float4*)(out + (bq * NHV + n) * HV + hc * 4) = zo;
    }
}

extern "C" void kernel_launch(void* const* d_in, const int* in_sizes, int n_in,
                              void* d_out, int out_size, void* d_ws, size_t ws_size,
                              hipStream_t stream) {
    const float* q   = (const float*)d_in[0];
    const float* k   = (const float*)d_in[1];
    const float* v   = (const float*)d_in[2];
    const int*   idx = (const int*)d_in[3];
    float*       out = (float*)d_out;

    const int n_units = BB * S2V * NHV;       // 32768 waves
    const int blocks  = n_units / 4;          // 8192 blocks of 4 waves
    rsa_kernel<<<blocks, 256, 0, stream>>>(q, k, v, idx, out);
}